// Round 7
// baseline (272.385 us; speedup 1.0000x reference)
//
#include <hip/hip_runtime.h>

// relu(x @ W^T + b): M=131072, K=256, N=256, f32 in/out.
// R11: get under the 64-VGPR occupancy cliff. R8/R10 both sat at 80 VGPR;
// m69 says wave-slots halve at vgpr={64,128,256}, so 80 allocates a
// 128-slot -> only 4 waves/SIMD regardless of blocks -> every round stuck
// at ~100us with all pipes <25% (latency-bound). Fix: halve the per-wave
// tile to 32x64 (acc 32 regs, one A row-frag), cap at exactly 64 via
// __launch_bounds__(512,4) (CUDA semantics: 4 blk x 8 waves / 4 SIMD = 8
// waves/EU -> 512/8 = 64). Full 32 waves/CU.
// Block: BM=64 x BN=256, 8 waves (2 row x 4 col groups of 32x64); 3 LDS
// buffers (24 KB); staging = exactly 1 global_load_lds per thread/chunk;
// counted vmcnt(1) schedule; XCD-bijective swizzle (2048%8==0).
// Math identical to verified R7-R10 (absmax 0.015625): W pre-split hi/lo
// bf16 fragment-order; x staged f32 with both-sides XOR swizzle;
// out = xh*wh + xh*wl + xl*wh via mfma_f32_32x32x16_bf16, fp32 acc.

typedef __attribute__((ext_vector_type(16))) float f32x16;
typedef __attribute__((ext_vector_type(8))) __bf16 bf16x8;

#define MFMA(a, b, c) \
    (c) = __builtin_amdgcn_mfma_f32_32x32x16_bf16((a), (b), (c), 0, 0, 0)

// Truncation split of 8 f32 into hi/lo bf16x8 fragments (verified R6-R10).
__device__ __forceinline__ void cvt8(const float4& A, const float4& B,
                                     bf16x8& hi, bf16x8& lo) {
    const float f[8] = {A.x, A.y, A.z, A.w, B.x, B.y, B.z, B.w};
#pragma unroll
    for (int j = 0; j < 8; ++j) {
        const unsigned int u = __builtin_bit_cast(unsigned int, f[j]);
        hi[j] = __builtin_bit_cast(__bf16, (unsigned short)(u >> 16));
        const float hf = __builtin_bit_cast(float, u & 0xffff0000u);
        const float lf = f[j] - hf;
        lo[j] = __builtin_bit_cast(__bf16,
                    (unsigned short)(__builtin_bit_cast(unsigned int, lf) >> 16));
    }
}

__device__ __forceinline__ void gload16(const float* g, float* l) {
    __builtin_amdgcn_global_load_lds(
        (const __attribute__((address_space(1))) void*)g,
        (__attribute__((address_space(3))) void*)l, 16, 0, 0);
}

// ---------------- W prep: f32 -> hi/lo bf16 in B-fragment order -------------
// Fragment F = col/32 (0..7); layout [F][t][lane] : (F*16+t)*512 + lane*8.
__global__ __launch_bounds__(256)
void wprep_kernel(const float* __restrict__ W,
                  __bf16* __restrict__ whi, __bf16* __restrict__ wlo) {
    const int wv = (int)blockIdx.x * 4 + (threadIdx.x >> 6);   // 0..127
    const int l  = threadIdx.x & 63;
    const int t  = wv & 15;          // k-step
    const int F  = wv >> 4;          // column fragment 0..7
    const int n  = F * 32 + (l & 31);
    const int k  = t * 16 + (l >> 5) * 8;
    const float4 A = *(const float4*)(W + n * 256 + k);
    const float4 B = *(const float4*)(W + n * 256 + k + 4);
    bf16x8 hi, lo;
    cvt8(A, B, hi, lo);
    *(bf16x8*)(whi + wv * 512 + l * 8) = hi;
    *(bf16x8*)(wlo + wv * 512 + l * 8) = lo;
}

// ---------------- main GEMM -------------------------------------------------
// (512, 4): CUDA-style minBlocksPerCU=4 -> 8 waves/EU -> VGPR cap exactly 64.
// Per-wave live state designed to ~64: acc 32 + A 8 + B 8 (per-j rotate) +
// LDS-read tmp 8 + addresses. If counters show >64 VGPR or WRITE_SIZE
// ballooning -> spill -> revert to 80-VGPR variant.
__global__ __launch_bounds__(512, 4)
void gemm_mfma_kernel(const float* __restrict__ x,
                      const __bf16* __restrict__ whi,
                      const __bf16* __restrict__ wlo,
                      const float* __restrict__ bias,
                      float* __restrict__ out) {
    // 3 buffers x 64 rows x 32 f32 = 24 KB
    __shared__ float xs[3][2048];

    const int tid  = threadIdx.x;       // 0..511
    const int lane = tid & 63;
    const int wid  = tid >> 6;          // 0..7
    const int wm   = wid >> 2;          // 0/1 : row group (32 rows each)
    const int wn   = wid & 3;           // 0..3: col group (64 cols each)

    // XCD swizzle: 2048 blocks, 8 XCDs, 2048%8==0 -> simple bijective form.
    const int bid = (int)blockIdx.x;
    const int rt  = (bid & 7) * 256 + (bid >> 3);

    const int r31 = lane & 31;
    const int g   = lane >> 5;
    const long row0 = (long)rt * 64;

    const int m0 = wm * 32 + r31;       // this lane's A row in the tile
    const int sw = r31 & 7;             // read-side XOR (m0&7 == r31&7)

    f32x16 acc0, acc1;                  // j=0 / j=1 accumulators (32 VGPR)
#pragma unroll
    for (int r = 0; r < 16; ++r) { acc0[r] = 0.f; acc1[r] = 0.f; }

    const int fbase0 = (wn * 2) * 16;   // first of this wave's 2 col-fragments
    const __bf16* whip = whi + (long)lane * 8;
    const __bf16* wlop = wlo + (long)lane * 8;

    // Stage one BK=32 chunk (64 rows x 32 f32 = 512 granules of 16B).
    // 512 threads -> exactly 1 gload_lds each. Linear LDS dest, swizzled src.
    auto STAGE = [&](int b, int chunk) {
        const int m = tid >> 3;                      // tile row 0..63
        const int cs = (tid & 7) ^ (m & 7);          // swizzled source granule
        const float* gp = x + (row0 + m) * 256 + chunk * 32 + cs * 4;
        float* lp = &xs[b][(wid * 64) * 4];          // wave-uniform base
        gload16(gp, lp);
    };

    // One t-step (k-width 16) from buffer xb: 2 ds_read_b128 + cvt + 6 MFMA.
    auto TSTEP = [&](const float* xb, int ks, int t) {
        const int c0 = t * 4 + g * 2;
        const float4 Aa = *(const float4*)(xb + m0 * 32 + ((c0 ^ sw) * 4));
        const float4 Ab = *(const float4*)(xb + m0 * 32 + (((c0 + 1) ^ sw) * 4));
        bf16x8 ah, al;
        cvt8(Aa, Ab, ah, al);
        const long f0 = (long)(fbase0 + ks) * 512;
        const long f1 = f0 + 16 * 512;
        {   // j = 0
            const bf16x8 bh = *(const bf16x8*)(whip + f0);
            const bf16x8 bl = *(const bf16x8*)(wlop + f0);
            MFMA(ah, bh, acc0); MFMA(ah, bl, acc0); MFMA(al, bh, acc0);
        }
        {   // j = 1
            const bf16x8 bh = *(const bf16x8*)(whip + f1);
            const bf16x8 bl = *(const bf16x8*)(wlop + f1);
            MFMA(ah, bh, acc1); MFMA(ah, bl, acc1); MFMA(al, bh, acc1);
        }
    };

    // Per-chunk phase: wait(stage c landed; keep newer in flight) -> raw
    // barrier -> compute (B-loads inside) -> STAGE(c+2) is issued first so
    // B consumption drains at most one stage generation (in-order vmcnt).
#define CHUNK(c, VM)                                                          \
    {                                                                         \
        asm volatile("s_waitcnt vmcnt(" VM ")" ::: "memory");                 \
        __builtin_amdgcn_s_barrier();                                         \
        if ((c) + 2 < 8) STAGE(((c) + 2) % 3, (c) + 2);                       \
        const float* xb = &xs[(c) % 3][0];                                    \
        TSTEP(xb, (c) * 2, 0);                                                \
        TSTEP(xb, (c) * 2 + 1, 1);                                            \
    }

    STAGE(0, 0);
    STAGE(1, 1);
    CHUNK(0, "1")
    CHUNK(1, "1")
    CHUNK(2, "1")
    CHUNK(3, "1")
    CHUNK(4, "1")
    CHUNK(5, "1")
    CHUNK(6, "1")
    CHUNK(7, "0")
#undef CHUNK

    // Epilogue: bias + ReLU. C/D map (verified m74/m101):
    // col = lane&31, row = (r&3) + 8*(r>>2) + 4*(lane>>5).
    const int  ocol0 = wn * 64;
    const long orow0 = row0 + wm * 32;
    const float bj0 = bias[ocol0 + r31];
    const float bj1 = bias[ocol0 + 32 + r31];

#pragma unroll
    for (int r = 0; r < 16; ++r) {
        const int rowf = (r & 3) + 8 * (r >> 2) + 4 * g;
        const long row = orow0 + rowf;
        float v0 = acc0[r] + bj0;
        float v1 = acc1[r] + bj1;
        v0 = v0 > 0.f ? v0 : 0.f;
        v1 = v1 > 0.f ? v1 : 0.f;
        out[row * 256 + ocol0 + r31]      = v0;
        out[row * 256 + ocol0 + 32 + r31] = v1;
    }
}

extern "C" void kernel_launch(void* const* d_in, const int* in_sizes, int n_in,
                              void* d_out, int out_size, void* d_ws, size_t ws_size,
                              hipStream_t stream) {
    (void)n_in; (void)ws_size; (void)out_size;
    const float* x = (const float*)d_in[0];
    const float* W = (const float*)d_in[1];
    const float* b = (const float*)d_in[2];
    float* out = (float*)d_out;

    __bf16* whi = (__bf16*)d_ws;             // 128 KB
    __bf16* wlo = whi + 65536;               // 128 KB

    wprep_kernel<<<32, 256, 0, stream>>>(W, whi, wlo);

    const int M = in_sizes[0] / 256;         // 131072
    const int grid = M / 64;                 // 2048 row tiles, whole N each
    gemm_mfma_kernel<<<grid, 512, 0, stream>>>(x, whi, wlo, b, out);
}